// Round 17
// baseline (31.227 us; speedup 1.0000x reference)
//
#include <hip/hip_runtime.h>
#include <hip/hip_fp16.h>

// DeformConv2d: x[8,64,56,56], offset[8,18,56,56], weight[64,64,3,3] -> out[8,64,56,56]
// prep (NHWC fp16 x + swizzled fp16 w) -> fused kernel with LDS-staged sample window:
// 8x4 px tile => clamped bilinear window fits [13 rows][17 cols][64ch] fp16 = 28.3 KB,
// staged COALESCED into LDS; corner fetches become ds_read_b128 (no scattered VMEM).
// Out-of-window corners (unbounded offsets, ~2 units/block) -> exec-masked global fallback.
// XCD batch-pinning (b = blk&7) kept from r14.

typedef _Float16 f16x8 __attribute__((ext_vector_type(8)));
typedef float    f32x4 __attribute__((ext_vector_type(4)));

namespace {
constexpr int Bn = 8, Cn = 64, Hn = 56, Wn = 56;
constexpr int Kk = 9, OCn = 64;
constexpr int NPIX = 56 * 56;      // 3136
constexpr int CK   = Cn * Kk;      // 576
constexpr int TP   = 32;           // px per block (8 wide x 4 tall)
constexpr int TXW  = 7;            // tiles across
constexpr int TILES = 98;          // 7 x 14
constexpr int XTILES = NPIX / 64;  // 49 (prep transpose tiles)
constexpr int KSTEPS = CK / 32;    // 18
constexpr int WR = 13, WC = 17;    // sample window rows/cols
constexpr int WSITES = WR * WC;    // 221 sites (128 B each)
constexpr int WU4 = WSITES * 8;    // 1768 uint4
}

__device__ __forceinline__ __half2 u2h(unsigned u) {
    union { unsigned u; __half2 h; } x; x.u = u; return x.h;
}
__device__ __forceinline__ unsigned bcast_h(float f) {
    unsigned short hs = __half_as_ushort(__float2half(f));
    return (unsigned)hs * 0x10001u;
}
__device__ __forceinline__ void lds_barrier() {
    asm volatile("s_waitcnt lgkmcnt(0)" ::: "memory");
    __builtin_amdgcn_s_barrier();
}

// prep: blocks [0,392): x NCHW fp32 -> NHWC fp16, batch = blk&7 (XCD-pinned).
//       blocks [392,536): w -> wh2 A-frag layout.
// wh2 uint4 index ((og*18+kk)*64+lane) = w[oc=og*16+(lane&15)][kglob=kk*32+(lane>>4)*8+j],
// kglob = tap*64 + c.
__global__ __launch_bounds__(256) void prep_kernel(
    const float* __restrict__ x, const float* __restrict__ w,
    unsigned short* __restrict__ xh, unsigned short* __restrict__ wh2)
{
    const int tid = threadIdx.x;
    if (blockIdx.x >= 392) {
        const int i = (blockIdx.x - 392) * 256 + tid;
        if (i < OCn * CK) {
            const int j    = i & 7;
            const int lane = (i >> 3) & 63;
            const int rest = i >> 9;           // og*18 + kk
            const int og   = rest / KSTEPS;
            const int oc   = og * 16 + (lane & 15);
            const int kglob = (rest % KSTEPS) * 32 + (lane >> 4) * 8 + j;
            const int tap = kglob >> 6;
            const int c   = kglob & 63;
            wh2[i] = __half_as_ushort(__float2half(w[oc * CK + c * Kk + tap]));
        }
        return;
    }
    __shared__ unsigned short lds[64][66];
    const int b  = blockIdx.x & 7;             // XCD-pinned batch
    const int t0 = (blockIdx.x >> 3) * 64;     // transpose tile within batch
    const float* xb = x + (size_t)b * Cn * NPIX;
    {
        const int hw0 = (tid & 15) * 4;
        #pragma unroll
        for (int i = 0; i < 4; ++i) {
            const int c = (tid >> 4) + i * 16;
            const float4 v = *(const float4*)(xb + (size_t)c * NPIX + t0 + hw0);
            lds[hw0 + 0][c] = __half_as_ushort(__float2half(v.x));
            lds[hw0 + 1][c] = __half_as_ushort(__float2half(v.y));
            lds[hw0 + 2][c] = __half_as_ushort(__float2half(v.z));
            lds[hw0 + 3][c] = __half_as_ushort(__float2half(v.w));
        }
    }
    __syncthreads();
    {
        const int co = (tid & 7) * 8;
        #pragma unroll
        for (int i = 0; i < 2; ++i) {
            const int hw = (tid >> 3) + i * 32;
            unsigned short tmp[8] __attribute__((aligned(16)));
            #pragma unroll
            for (int j = 0; j < 8; ++j) tmp[j] = lds[hw][co + j];
            *(uint4*)(xh + ((size_t)b * NPIX + t0 + hw) * Cn + co) = *(const uint4*)tmp;
        }
    }
}

// Fused: block = 8x4 px tile x 64 oc, 256 threads. batch = blk&7, tile = blk>>3.
__global__ __launch_bounds__(256, 3) void deform_fused(
    const unsigned short* __restrict__ xh, const float* __restrict__ off,
    const unsigned short* __restrict__ wh2, float* __restrict__ out)
{
    __shared__ uint4 smpw[Kk * TP];                  // 4608 B: bilinear weights
    __shared__ int4  smpa[Kk * TP];                  // 4608 B: global fallback offsets
    __shared__ int4  smpl[Kk * TP];                  // 4608 B: window uint4-index or -1
    __shared__ __align__(16) uint4 win[WU4];         // 28288 B: sample window
    __shared__ __align__(16) uint4 vbuf[2][8 * TP];  // 8192 B

    const int tid = threadIdx.x;
    const int b   = blockIdx.x & 7;            // XCD-pinned batch
    const int t   = blockIdx.x >> 3;           // 0..97
    const int ox0 = (t % TXW) * 8;
    const int oy0 = (t / TXW) * 4;
    const int r0  = min(max(oy0 - 4, 0), Hn - WR);   // window origin row
    const int c0  = min(max(ox0 - 4, 0), Wn - WC);   // window origin col
    const unsigned short* xb = xh + (size_t)b * NPIX * Cn;
    const float* offb = off + (size_t)b * 18 * NPIX;

    // ---- issue window staging loads (coalesced: 136 consecutive uint4 per row) ----
    uint4 st[7];
    #pragma unroll
    for (int it = 0; it < 7; ++it) {
        const int u = tid + 256 * it;
        if (u < WU4) {
            const int i   = u / 136;           // window row
            const int rem = u - i * 136;       // (col, oct) packed
            st[it] = *(const uint4*)(xb + ((size_t)((r0 + i) * Wn + c0)) * Cn + rem * 8);
        }
    }

    // ---- metadata: entry per (tap, px); px -> (oy0+px>>3, ox0+px&7) ----
    for (int e = tid; e < Kk * TP; e += 256) {
        const int k  = e >> 5;
        const int px = e & 31;
        const int oy = oy0 + (px >> 3);
        const int ox = ox0 + (px & 7);
        const int p  = oy * Wn + ox;
        const int ki = k / 3, kj = k % 3;
        const float offy = offb[(size_t)(2 * k)     * NPIX + p];
        const float offx = offb[(size_t)(2 * k + 1) * NPIX + p];
        const float py  = offy + (float)(oy - 1 + ki);
        const float pxv = offx + (float)(ox - 1 + kj);
        const float y0f = floorf(py), x0f = floorf(pxv);
        const float ty = py - y0f, tx = pxv - x0f;
        const int y0 = (int)y0f, x0 = (int)x0f;
        const int y1 = y0 + 1, x1 = x0 + 1;
        const bool vy0 = (y0 >= 0) & (y0 < Hn);
        const bool vy1 = (y1 >= 0) & (y1 < Hn);
        const bool vx0 = (x0 >= 0) & (x0 < Wn);
        const bool vx1 = (x1 >= 0) & (x1 < Wn);
        const int cy0 = min(max(y0, 0), Hn - 1);
        const int cy1 = min(max(y1, 0), Hn - 1);
        const int cx0 = min(max(x0, 0), Wn - 1);
        const int cx1 = min(max(x1, 0), Wn - 1);
        uint4 wq;
        wq.x = bcast_h((vy0 && vx0) ? (1.f - ty) * (1.f - tx) : 0.f);
        wq.y = bcast_h((vy0 && vx1) ? (1.f - ty) * tx         : 0.f);
        wq.z = bcast_h((vy1 && vx0) ? ty * (1.f - tx)         : 0.f);
        wq.w = bcast_h((vy1 && vx1) ? ty * tx                 : 0.f);
        int4 av;
        av.x = (cy0 * Wn + cx0) * Cn;
        av.y = (cy0 * Wn + cx1) * Cn;
        av.z = (cy1 * Wn + cx0) * Cn;
        av.w = (cy1 * Wn + cx1) * Cn;
        // window uint4-index (site*8) or -1 sentinel
        const int i00y = cy0 - r0, i00x = cx0 - c0;
        const int i11y = cy1 - r0, i11x = cx1 - c0;
        int4 wl;
        wl.x = ((unsigned)i00y < WR && (unsigned)i00x < WC) ? (i00y * WC + i00x) * 8 : -1;
        wl.y = ((unsigned)i00y < WR && (unsigned)i11x < WC) ? (i00y * WC + i11x) * 8 : -1;
        wl.z = ((unsigned)i11y < WR && (unsigned)i00x < WC) ? (i11y * WC + i00x) * 8 : -1;
        wl.w = ((unsigned)i11y < WR && (unsigned)i11x < WC) ? (i11y * WC + i11x) * 8 : -1;
        smpw[e] = wq;
        smpa[e] = av;
        smpl[e] = wl;
    }

    // ---- commit staging to LDS ----
    #pragma unroll
    for (int it = 0; it < 7; ++it) {
        const int u = tid + 256 * it;
        if (u < WU4) win[u] = st[it];
    }
    __syncthreads();

    // thread -> gather unit: oct = tid&7, px = (tid>>3)&31
    const int oct = tid & 7;
    const int gpx = (tid >> 3) & 31;
    const int co8 = oct * 8;

    // GEMM ids: wave = og (16 oc) x 32 px
    const int lane = tid & 63;
    const int og   = tid >> 6;
    const int hi   = lane >> 4;
    const int lr   = lane & 15;
    const uint4* ab = (const uint4*)wh2 + (size_t)og * KSTEPS * 64 + lane;

    uint4 aF[2][2];
    f32x4 acc0 = {0.f, 0.f, 0.f, 0.f};
    f32x4 acc1 = {0.f, 0.f, 0.f, 0.f};

    auto loadA = [&](int k) {
        aF[k & 1][0] = ab[(k * 2 + 0) * 64];
        aF[k & 1][1] = ab[(k * 2 + 1) * 64];
    };
    auto blend = [&](int k) {
        const int m = k * TP + gpx;
        const uint4 wq = smpw[m];
        const int4  av = smpa[m];
        const int4  wl = smpl[m];
        uint4 v0 = win[(wl.x < 0 ? 0 : wl.x) + oct];
        uint4 v1 = win[(wl.y < 0 ? 0 : wl.y) + oct];
        uint4 v2 = win[(wl.z < 0 ? 0 : wl.z) + oct];
        uint4 v3 = win[(wl.w < 0 ? 0 : wl.w) + oct];
        if (wl.x < 0) v0 = *(const uint4*)(xb + av.x + co8);   // rare fallback
        if (wl.y < 0) v1 = *(const uint4*)(xb + av.y + co8);
        if (wl.z < 0) v2 = *(const uint4*)(xb + av.z + co8);
        if (wl.w < 0) v3 = *(const uint4*)(xb + av.w + co8);
        const __half2 w00 = u2h(wq.x), w01 = u2h(wq.y);
        const __half2 w10 = u2h(wq.z), w11 = u2h(wq.w);
        uint4 res;
        unsigned* rp = (unsigned*)&res;
        #pragma unroll
        for (int q = 0; q < 4; ++q) {
            __half2 a = __hmul2(w00, u2h(((const unsigned*)&v0)[q]));
            a = __hfma2(w01, u2h(((const unsigned*)&v1)[q]), a);
            a = __hfma2(w10, u2h(((const unsigned*)&v2)[q]), a);
            a = __hfma2(w11, u2h(((const unsigned*)&v3)[q]), a);
            rp[q] = *(const unsigned*)&a;
        }
        vbuf[k & 1][oct * TP + gpx] = res;
    };
    auto mfma = [&](int k) {
        #pragma unroll
        for (int kl = 0; kl < 2; ++kl) {
            const int octr = kl * 4 + hi;
            union { uint4 u; f16x8 h; } a, b0, b1;
            a.u  = aF[k & 1][kl];
            b0.u = vbuf[k & 1][octr * TP + lr];
            b1.u = vbuf[k & 1][octr * TP + 16 + lr];
            acc0 = __builtin_amdgcn_mfma_f32_16x16x32_f16(a.h, b0.h, acc0, 0, 0, 0);
            acc1 = __builtin_amdgcn_mfma_f32_16x16x32_f16(a.h, b1.h, acc1, 0, 0, 0);
        }
    };

    loadA(0);
    #pragma unroll
    for (int k = 0; k < Kk; ++k) {
        if (k < Kk - 1) loadA(k + 1);   // A one chunk ahead (plain loads, compiler waits)
        blend(k);                       // corners from LDS window
        lds_barrier();                  // vbuf writes visible; also separates buffer reuse
        mfma(k);
    }

    // D: px' = lr (and 16+lr) -> (oy0 + px'>>3, ox0 + px'&7); row(oc) = og*16+hi*4+r
    const int p_lo = (oy0 + (lr >> 3)) * Wn + ox0 + (lr & 7);
    const int p_hi = (oy0 + 2 + (lr >> 3)) * Wn + ox0 + (lr & 7);
    float* ob = out + ((size_t)b * OCn + og * 16 + hi * 4) * NPIX;
    #pragma unroll
    for (int r = 0; r < 4; ++r) {
        ob[(size_t)r * NPIX + p_lo] = acc0[r];
        ob[(size_t)r * NPIX + p_hi] = acc1[r];
    }
}

extern "C" void kernel_launch(void* const* d_in, const int* in_sizes, int n_in,
                              void* d_out, int out_size, void* d_ws, size_t ws_size,
                              hipStream_t stream) {
    const float* x   = (const float*)d_in[0];
    const float* off = (const float*)d_in[1];
    const float* w   = (const float*)d_in[2];
    float* out = (float*)d_out;
    unsigned short* wh2 = (unsigned short*)d_ws;                    // 73728 B
    unsigned short* xh  = (unsigned short*)((char*)d_ws + 131072);  // 3.21 MB

    hipLaunchKernelGGL(prep_kernel, dim3(392 + 144), dim3(256), 0, stream, x, w, xh, wh2);
    hipLaunchKernelGGL(deform_fused, dim3(Bn * TILES), dim3(256), 0, stream,
                       xh, off, wh2, out);
}

// Round 18
// 21.704 us; speedup vs baseline: 1.4388x; 1.4388x over previous
//
#include <hip/hip_runtime.h>
#include <hip/hip_fp16.h>

// DeformConv2d: x[8,64,56,56], offset[8,18,56,56], weight[64,64,3,3] -> out[8,64,56,56]
// prep (NHWC fp16 x + swizzled fp16 w) -> fused kernel with PRODUCER/CONSUMER wave
// specialization: waves 0-1 gather+blend (asm-pinned depth-2, private vmcnt), waves 2-5
// MFMA+A-prefetch (private vmcnt). vbuf ring-3, one lgkm barrier per tap. 2D 8x4 px
// tiles, XCD batch-pinning (b=blk&7).

typedef _Float16 f16x8 __attribute__((ext_vector_type(8)));
typedef float    f32x4 __attribute__((ext_vector_type(4)));

namespace {
constexpr int Bn = 8, Cn = 64, Hn = 56, Wn = 56;
constexpr int Kk = 9, OCn = 64;
constexpr int NPIX = 56 * 56;      // 3136
constexpr int CK   = Cn * Kk;      // 576
constexpr int TP   = 32;           // px per block (8 wide x 4 tall)
constexpr int TXW  = 7;            // tiles across
constexpr int TILES = 98;          // 7 x 14
constexpr int XTILES = NPIX / 64;  // 49 (prep transpose tiles)
constexpr int KSTEPS = CK / 32;    // 18
constexpr int NTHR = 384;          // 6 waves: 2 producer + 4 consumer
}

__device__ __forceinline__ __half2 u2h(unsigned u) {
    union { unsigned u; __half2 h; } x; x.u = u; return x.h;
}
__device__ __forceinline__ unsigned bcast_h(float f) {
    unsigned short hs = __half_as_ushort(__float2half(f));
    return (unsigned)hs * 0x10001u;
}
__device__ __forceinline__ void lds_barrier() {
    asm volatile("s_waitcnt lgkmcnt(0)" ::: "memory");
    __builtin_amdgcn_s_barrier();
}
// Position-pinned 16B global load (async; pair with explicit vmcnt waits).
__device__ __forceinline__ void gld16(uint4& d, const unsigned short* p) {
    asm volatile("global_load_dwordx4 %0, %1, off" : "=&v"(d) : "v"(p) : "memory");
}

// prep: blocks [0,392): x NCHW fp32 -> NHWC fp16, batch = blk&7 (XCD-pinned).
//       blocks [392,536): w -> wh2 A-frag layout.
// wh2 uint4 index ((og*18+kk)*64+lane) = w[oc=og*16+(lane&15)][kglob=kk*32+(lane>>4)*8+j],
// kglob = tap*64 + c.
__global__ __launch_bounds__(256) void prep_kernel(
    const float* __restrict__ x, const float* __restrict__ w,
    unsigned short* __restrict__ xh, unsigned short* __restrict__ wh2)
{
    const int tid = threadIdx.x;
    if (blockIdx.x >= 392) {
        const int i = (blockIdx.x - 392) * 256 + tid;
        if (i < OCn * CK) {
            const int j    = i & 7;
            const int lane = (i >> 3) & 63;
            const int rest = i >> 9;           // og*18 + kk
            const int og   = rest / KSTEPS;
            const int oc   = og * 16 + (lane & 15);
            const int kglob = (rest % KSTEPS) * 32 + (lane >> 4) * 8 + j;
            const int tap = kglob >> 6;
            const int c   = kglob & 63;
            wh2[i] = __half_as_ushort(__float2half(w[oc * CK + c * Kk + tap]));
        }
        return;
    }
    __shared__ unsigned short lds[64][66];
    const int b  = blockIdx.x & 7;             // XCD-pinned batch
    const int t0 = (blockIdx.x >> 3) * 64;     // transpose tile within batch
    const float* xb = x + (size_t)b * Cn * NPIX;
    {
        const int hw0 = (tid & 15) * 4;
        #pragma unroll
        for (int i = 0; i < 4; ++i) {
            const int c = (tid >> 4) + i * 16;
            const float4 v = *(const float4*)(xb + (size_t)c * NPIX + t0 + hw0);
            lds[hw0 + 0][c] = __half_as_ushort(__float2half(v.x));
            lds[hw0 + 1][c] = __half_as_ushort(__float2half(v.y));
            lds[hw0 + 2][c] = __half_as_ushort(__float2half(v.z));
            lds[hw0 + 3][c] = __half_as_ushort(__float2half(v.w));
        }
    }
    __syncthreads();
    {
        const int co = (tid & 7) * 8;
        #pragma unroll
        for (int i = 0; i < 2; ++i) {
            const int hw = (tid >> 3) + i * 32;
            unsigned short tmp[8] __attribute__((aligned(16)));
            #pragma unroll
            for (int j = 0; j < 8; ++j) tmp[j] = lds[hw][co + j];
            *(uint4*)(xh + ((size_t)b * NPIX + t0 + hw) * Cn + co) = *(const uint4*)tmp;
        }
    }
}

// Fused: block = 8x4 px tile x 64 oc, 384 threads (2 producer + 4 consumer waves).
__global__ __launch_bounds__(NTHR, 3) void deform_fused(
    const unsigned short* __restrict__ xh, const float* __restrict__ off,
    const unsigned short* __restrict__ wh2, float* __restrict__ out)
{
    __shared__ uint4 smpw[Kk * TP];            // 4608 B
    __shared__ int4  smpa[Kk * TP];            // 4608 B
    __shared__ __align__(16) uint4 vbuf[3][8 * TP];   // 12288 B

    const int tid = threadIdx.x;
    const int b   = blockIdx.x & 7;            // XCD-pinned batch
    const int t   = blockIdx.x >> 3;           // 0..97
    const int ox0 = (t % TXW) * 8;
    const int oy0 = (t / TXW) * 4;
    const unsigned short* xb = xh + (size_t)b * NPIX * Cn;
    const float* offb = off + (size_t)b * 18 * NPIX;

    // ---- metadata: entry per (tap, px); px -> (oy0+px>>3, ox0+px&7) ----
    for (int e = tid; e < Kk * TP; e += NTHR) {
        const int k  = e >> 5;
        const int px = e & 31;
        const int oy = oy0 + (px >> 3);
        const int ox = ox0 + (px & 7);
        const int p  = oy * Wn + ox;
        const int ki = k / 3, kj = k % 3;
        const float offy = offb[(size_t)(2 * k)     * NPIX + p];
        const float offx = offb[(size_t)(2 * k + 1) * NPIX + p];
        const float py  = offy + (float)(oy - 1 + ki);
        const float pxv = offx + (float)(ox - 1 + kj);
        const float y0f = floorf(py), x0f = floorf(pxv);
        const float ty = py - y0f, tx = pxv - x0f;
        const int y0 = (int)y0f, x0 = (int)x0f;
        const int y1 = y0 + 1, x1 = x0 + 1;
        const bool vy0 = (y0 >= 0) & (y0 < Hn);
        const bool vy1 = (y1 >= 0) & (y1 < Hn);
        const bool vx0 = (x0 >= 0) & (x0 < Wn);
        const bool vx1 = (x1 >= 0) & (x1 < Wn);
        const int cy0 = min(max(y0, 0), Hn - 1);
        const int cy1 = min(max(y1, 0), Hn - 1);
        const int cx0 = min(max(x0, 0), Wn - 1);
        const int cx1 = min(max(x1, 0), Wn - 1);
        uint4 wq;
        wq.x = bcast_h((vy0 && vx0) ? (1.f - ty) * (1.f - tx) : 0.f);
        wq.y = bcast_h((vy0 && vx1) ? (1.f - ty) * tx         : 0.f);
        wq.z = bcast_h((vy1 && vx0) ? ty * (1.f - tx)         : 0.f);
        wq.w = bcast_h((vy1 && vx1) ? ty * tx                 : 0.f);
        int4 av;
        av.x = (cy0 * Wn + cx0) * Cn;
        av.y = (cy0 * Wn + cx1) * Cn;
        av.z = (cy1 * Wn + cx0) * Cn;
        av.w = (cy1 * Wn + cx1) * Cn;
        smpw[e] = wq;
        smpa[e] = av;
    }
    lds_barrier();
    asm volatile("s_waitcnt vmcnt(0)" ::: "memory");   // zero every wave's counter

    const int wv = tid >> 6;     // 0..5

    if (wv < 2) {
        // ===== producers: 128 threads, 2 gather units per tap =====
        const int oct  = tid & 7;
        const int gpx0 = (tid >> 3) & 15;
        const int co   = oct * 8;

        uint4 s0[2][2], s1[2][2], s2[2][2], s3[2][2], wqr[2][2];  // [slot][unit]

        auto stageC = [&](int k) {              // 8 pinned corner loads
            const int sl = k & 1;
            #pragma unroll
            for (int u = 0; u < 2; ++u) {
                const int m  = k * TP + gpx0 + u * 16;
                const int4 av = smpa[m];
                wqr[sl][u] = smpw[m];
                gld16(s0[sl][u], xb + av.x + co);
                gld16(s1[sl][u], xb + av.y + co);
                gld16(s2[sl][u], xb + av.z + co);
                gld16(s3[sl][u], xb + av.w + co);
            }
        };
        auto blend = [&](int k) {
            const int sl = k & 1;
            #pragma unroll
            for (int u = 0; u < 2; ++u) {
                const __half2 w00 = u2h(wqr[sl][u].x), w01 = u2h(wqr[sl][u].y);
                const __half2 w10 = u2h(wqr[sl][u].z), w11 = u2h(wqr[sl][u].w);
                uint4 res;
                unsigned* rp = (unsigned*)&res;
                #pragma unroll
                for (int q = 0; q < 4; ++q) {
                    __half2 a = __hmul2(w00, u2h(((const unsigned*)&s0[sl][u])[q]));
                    a = __hfma2(w01, u2h(((const unsigned*)&s1[sl][u])[q]), a);
                    a = __hfma2(w10, u2h(((const unsigned*)&s2[sl][u])[q]), a);
                    a = __hfma2(w11, u2h(((const unsigned*)&s3[sl][u])[q]), a);
                    rp[q] = *(const unsigned*)&a;
                }
                vbuf[k % 3][oct * TP + gpx0 + u * 16] = res;
            }
        };

        stageC(0); stageC(1);                          // 16 outstanding
        asm volatile("s_waitcnt vmcnt(8)" ::: "memory");
        __builtin_amdgcn_sched_barrier(0);
        blend(0);
        lds_barrier();                                 // prologue barrier

        #pragma unroll
        for (int k = 0; k < Kk; ++k) {
            if (k < Kk - 2) {
                stageC(k + 2);                         // +8 -> 16 outstanding
                asm volatile("s_waitcnt vmcnt(8)" ::: "memory");
            } else if (k == Kk - 2) {
                asm volatile("s_waitcnt vmcnt(0)" ::: "memory");
            }
            __builtin_amdgcn_sched_barrier(0);
            if (k < Kk - 1) blend(k + 1);
            lds_barrier();
        }
    } else {
        // ===== consumers: waves 2-5, og = wv-2, 16 oc x 32 px =====
        const int lane = tid & 63;
        const int og   = wv - 2;
        const int hi   = lane >> 4;
        const int lr   = lane & 15;
        const uint4* ab = (const uint4*)wh2 + (size_t)og * KSTEPS * 64 + lane;

        uint4 aF[2][2];
        f32x4 acc0 = {0.f, 0.f, 0.f, 0.f};
        f32x4 acc1 = {0.f, 0.f, 0.f, 0.f};

        auto loadA = [&](int k) {
            gld16(aF[k & 1][0], (const unsigned short*)(ab + (k * 2 + 0) * 64));
            gld16(aF[k & 1][1], (const unsigned short*)(ab + (k * 2 + 1) * 64));
        };
        auto mfma = [&](int k) {
            #pragma unroll
            for (int kl = 0; kl < 2; ++kl) {
                const int octr = kl * 4 + hi;
                union { uint4 u; f16x8 h; } a, b0, b1;
                a.u  = aF[k & 1][kl];
                b0.u = vbuf[k % 3][octr * TP + lr];
                b1.u = vbuf[k % 3][octr * TP + 16 + lr];
                acc0 = __builtin_amdgcn_mfma_f32_16x16x32_f16(a.h, b0.h, acc0, 0, 0, 0);
                acc1 = __builtin_amdgcn_mfma_f32_16x16x32_f16(a.h, b1.h, acc1, 0, 0, 0);
            }
        };

        loadA(0);                                      // 2 outstanding
        lds_barrier();                                 // prologue barrier

        #pragma unroll
        for (int k = 0; k < Kk; ++k) {
            if (k < Kk - 1) {
                loadA(k + 1);                          // +2 -> 4 outstanding
                asm volatile("s_waitcnt vmcnt(2)" ::: "memory");
            } else {
                asm volatile("s_waitcnt vmcnt(0)" ::: "memory");
            }
            __builtin_amdgcn_sched_barrier(0);
            mfma(k);                                   // aF[k] landed; vbuf[k%3] ready
            lds_barrier();
        }

        // D: px' = lr (and 16+lr) -> (oy0 + px'>>3, ox0 + px'&7); row = og*16+hi*4+r
        const int p_lo = (oy0 + (lr >> 3)) * Wn + ox0 + (lr & 7);
        const int p_hi = (oy0 + 2 + (lr >> 3)) * Wn + ox0 + (lr & 7);
        float* ob = out + ((size_t)b * OCn + og * 16 + hi * 4) * NPIX;
        #pragma unroll
        for (int r = 0; r < 4; ++r) {
            ob[(size_t)r * NPIX + p_lo] = acc0[r];
            ob[(size_t)r * NPIX + p_hi] = acc1[r];
        }
    }
}

extern "C" void kernel_launch(void* const* d_in, const int* in_sizes, int n_in,
                              void* d_out, int out_size, void* d_ws, size_t ws_size,
                              hipStream_t stream) {
    const float* x   = (const float*)d_in[0];
    const float* off = (const float*)d_in[1];
    const float* w   = (const float*)d_in[2];
    float* out = (float*)d_out;
    unsigned short* wh2 = (unsigned short*)d_ws;                    // 73728 B
    unsigned short* xh  = (unsigned short*)((char*)d_ws + 131072);  // 3.21 MB

    hipLaunchKernelGGL(prep_kernel, dim3(392 + 144), dim3(256), 0, stream, x, w, xh, wh2);
    hipLaunchKernelGGL(deform_fused, dim3(Bn * TILES), dim3(NTHR), 0, stream,
                       xh, off, wh2, out);
}